// Round 7
// baseline (49.251 us; speedup 1.0000x reference)
//
#include <hip/hip_runtime.h>
#include <math.h>
#include <stdint.h>

// EdgeLayer: out[b,o] = min_j ( x[b,j] + mask[o,j] ),
// mask = bernoulli(km, softmax(edges)[...,1]), JAX partitionable threefry,
// 32-bit draws = bits1 ^ bits2.  (Bit-exact, proven R4/R5/R6: absmax = 0.)
//
// Identity (proven on-data in R6):
//   out[b,o] = min( g_b + 1.0f, min{ x[b,j] : x[b,j] < g_b+1, mask[o,j]=0 } )
// with g_b = min_j x[b,j].  ~11 candidates/row (Phi(-2.54)*2048).
//
// R7: ONE fused kernel, no workspace. Every block (256 blocks, 8 o's each)
// redundantly builds all 32 rows' sorted candidate lists in LDS (x is
// L2-resident; rank sort is barrier-free, deterministic via column-index
// tie-break), then walks candidates ascending with 8-deep edge prefetch and
// early exit at the first unmasked bit (~2.5 probes expected).
// B=32, IN_F=2048, OUT_F=2048, f32.

#define BATCH 32
#define INFEAT 2048
#define OUTFEAT 2048
#define CAP 64       // P(cnt>64) ~ 1e-30; exact dense fallback kept anyway
#define RSTRIDE 65   // LDS row stride (65 = 1 mod 32: walk reads conflict-free)

struct U2 { uint32_t a, b; };

__host__ __device__ constexpr uint32_t rotl32c(uint32_t x, int r) {
  return (x << r) | (x >> (32 - r));
}

// Exact JAX/Random123 threefry2x32: 20 rounds, both output words.
__host__ __device__ constexpr U2 tf2x32(uint32_t k0, uint32_t k1,
                                        uint32_t x0, uint32_t x1) {
  const uint32_t ks2 = k0 ^ k1 ^ 0x1BD11BDAu;
#define RND(r) { x0 += x1; x1 = rotl32c(x1, (r)); x1 ^= x0; }
  x0 += k0; x1 += k1;
  RND(13) RND(15) RND(26) RND(6)
  x0 += k1; x1 += ks2 + 1u;
  RND(17) RND(29) RND(16) RND(24)
  x0 += ks2; x1 += k0 + 2u;
  RND(13) RND(15) RND(26) RND(6)
  x0 += k0; x1 += k1 + 3u;
  RND(17) RND(29) RND(16) RND(24)
  x0 += k1; x1 += ks2 + 4u;
  RND(13) RND(15) RND(26) RND(6)
  x0 += ks2; x1 += k0 + 5u;
#undef RND
  return U2{x0, x1};
}

// km = split(key(42))[0] under partitionable split: full (y0,y1) of tf(key;0,0)
constexpr U2 KM = tf2x32(0u, 42u, 0u, 0u);

__device__ __forceinline__ float u01_from_bits(uint32_t bits) {
  return __uint_as_float((bits >> 9) | 0x3f800000u) - 1.0f;
}

// softmax(edges,-1)[...,1] in f32; single nontrivial exp via double
// (bit-exact vs reference, proven R4).
__device__ __forceinline__ float prob_edge(float e0, float e1) {
  const float d = e1 - e0;
  const float a = -fabsf(d);
  const float t = (float)exp((double)a);
  return (d >= 0.0f) ? (1.0f / (t + 1.0f)) : (t / (1.0f + t));
}

// Bernoulli mask bit for (o, j): true = edge present (mask adds +1.0f)
__device__ __forceinline__ bool edge_bit(int o, int j, float e0, float e1) {
  const uint32_t n = (uint32_t)(o * INFEAT + j);
  const U2 y = tf2x32(KM.a, KM.b, 0u, n);
  return u01_from_bits(y.a ^ y.b) < prob_edge(e0, e1);
}

__global__ __launch_bounds__(256) void edge_min_fused(
    const float* __restrict__ x,      // [32][2048]
    const float* __restrict__ edges,  // [2048][2048][2]
    float* __restrict__ out) {        // [32][2048]
  __shared__ float thrL[BATCH];
  __shared__ int   cntL[BATCH];
  __shared__ float sx [BATCH * RSTRIDE];   // unsorted candidates
  __shared__ int   sj [BATCH * RSTRIDE];
  __shared__ float ssx[BATCH * RSTRIDE];   // rank-sorted candidates
  __shared__ int   ssj[BATCH * RSTRIDE];

  const int tid  = threadIdx.x;
  const int lane = tid & 63;
  const int wv   = tid >> 6;               // 4 waves

  if (tid < BATCH) cntL[tid] = 0;
  __syncthreads();

  // ---- Phase A1: per-row min + candidate collection (wave handles 8 rows) --
  const float4* x4 = (const float4*)x;
#pragma unroll
  for (int rr = 0; rr < 8; ++rr) {
    const int b = wv * 8 + rr;
    float4 v[8];
#pragma unroll
    for (int k = 0; k < 8; ++k) v[k] = x4[b * (INFEAT / 4) + k * 64 + lane];
    float lm = INFINITY;
#pragma unroll
    for (int k = 0; k < 8; ++k)
      lm = fminf(lm, fminf(fminf(v[k].x, v[k].y), fminf(v[k].z, v[k].w)));
#pragma unroll
    for (int off = 32; off > 0; off >>= 1)
      lm = fminf(lm, __shfl_xor(lm, off, 64));
    const float thr = lm + 1.0f;           // exact; same rounding as reference
    if (lane == 0) thrL[b] = thr;
#pragma unroll
    for (int k = 0; k < 8; ++k) {
      const int j0 = (k * 64 + lane) * 4;
      const float c[4] = {v[k].x, v[k].y, v[k].z, v[k].w};
#pragma unroll
      for (int q = 0; q < 4; ++q) {
        if (c[q] < thr) {
          const int idx = atomicAdd(&cntL[b], 1);
          if (idx < CAP) { sx[b * RSTRIDE + idx] = c[q]; sj[b * RSTRIDE + idx] = j0 + q; }
        }
      }
    }
  }
  __syncthreads();

  // ---- Phase A2: barrier-free rank sort (deterministic: tie-break by j) ----
  for (int s = tid; s < BATCH * CAP; s += 256) {
    const int b = s >> 6;            // row
    const int i = s & (CAP - 1);     // slot
    const int cnt = min(cntL[b], CAP);
    if (i < cnt) {
      const float xi = sx[b * RSTRIDE + i];
      const int   ji = sj[b * RSTRIDE + i];
      int rank = 0;
      for (int k = 0; k < cnt; ++k) {
        const float xk = sx[b * RSTRIDE + k];
        const int   jk = sj[b * RSTRIDE + k];
        rank += (xk < xi) || (xk == xi && jk < ji);
      }
      ssx[b * RSTRIDE + rank] = xi;
      ssj[b * RSTRIDE + rank] = ji;
    }
  }
  __syncthreads();

  // ---- Phase B: candidate walk, early exit at first unmasked bit ----------
  const int b = tid & 31;
  const int o = blockIdx.x * 8 + (tid >> 5);
  const float thr = thrL[b];
  const int   cnt = cntL[b];
  const float2* e2 = (const float2*)edges;

  float res;
  if (cnt > CAP) {
    // exact dense fallback -- statistically unreachable, kept for rigor
    float m = INFINITY;
    for (int j = 0; j < INFEAT; ++j) {
      const float2 e = e2[o * INFEAT + j];
      const float bit = edge_bit(o, j, e.x, e.y) ? 1.0f : 0.0f;
      m = fminf(m, x[b * INFEAT + j] + bit);
    }
    res = m;
  } else {
    float m0 = INFINITY;
    bool done = false;
    for (int base = 0; base < cnt && !done; base += 8) {
      // batch-prefetch 8 candidates' edges (independent loads, one round-trip)
      float cx[8]; int cj[8]; float ce0[8], ce1[8];
#pragma unroll
      for (int k = 0; k < 8; ++k) {
        const bool act = (base + k) < cnt;
        cx[k] = act ? ssx[b * RSTRIDE + base + k] : 0.0f;
        cj[k] = act ? ssj[b * RSTRIDE + base + k] : 0;
        const float2 e = e2[o * INFEAT + cj[k]];   // j=0 safe when inactive
        ce0[k] = e.x; ce1[k] = e.y;
      }
#pragma unroll
      for (int k = 0; k < 8; ++k) {
        const bool act = (base + k) < cnt;
        if (!done && act && !edge_bit(o, cj[k], ce0[k], ce1[k])) {
          m0 = cx[k];
          done = true;
        }
      }
    }
    res = fminf(m0, thr);
  }
  out[b * OUTFEAT + o] = res;
}

extern "C" void kernel_launch(void* const* d_in, const int* in_sizes, int n_in,
                              void* d_out, int out_size, void* d_ws, size_t ws_size,
                              hipStream_t stream) {
  const float* x     = (const float*)d_in[0];   // 32*2048
  const float* edges = (const float*)d_in[1];   // 2048*2048*2
  float* out = (float*)d_out;                   // 32*2048
  (void)in_sizes; (void)n_in; (void)out_size; (void)d_ws; (void)ws_size;

  hipLaunchKernelGGL(edge_min_fused, dim3(OUTFEAT / 8), dim3(256), 0, stream,
                     x, edges, out);
}

// Round 8
// 24.094 us; speedup vs baseline: 2.0441x; 2.0441x over previous
//
#include <hip/hip_runtime.h>
#include <math.h>
#include <stdint.h>

// EdgeLayer: out[b,o] = min_j ( x[b,j] + mask[o,j] ),
// mask = bernoulli(km, softmax(edges)[...,1]), JAX partitionable threefry,
// 32-bit draws = bits1 ^ bits2.  (Bit-exact, proven R4-R7: absmax = 0.)
//
// Identity (proven on-data R6/R7):
//   out[b,o] = min( g_b + 1.0f, min{ x[b,j] : x[b,j] < g_b+1, mask[o,j]=0 } )
// with g_b = min_j x[b,j].  ~11 candidates/row (Phi(-2.54)*2048).
//
// R8: single launch, block = 4 rows x 64 o (grid 8x32=256).  Wave w preps
// ONE row (8KB x-read, wave reduce, LDS collect, rank sort) then walks that
// row for its 64 o's (lane = o).  Per-block prep is 32KB/4-serial-chains
// lighter than R7's 256KB/32-chains -- that redundancy was R7's regression.
// B=32, IN_F=2048, OUT_F=2048, f32.

#define BATCH 32
#define INFEAT 2048
#define OUTFEAT 2048
#define CAP 64        // P(cnt>64) ~ 1e-30; exact dense fallback kept anyway
#define ROWS_PB 4     // rows per block (one per wave)
#define OS_PB   64    // o-values per block (one per lane)

struct U2 { uint32_t a, b; };

__host__ __device__ constexpr uint32_t rotl32c(uint32_t x, int r) {
  return (x << r) | (x >> (32 - r));
}

// Exact JAX/Random123 threefry2x32: 20 rounds, both output words.
__host__ __device__ constexpr U2 tf2x32(uint32_t k0, uint32_t k1,
                                        uint32_t x0, uint32_t x1) {
  const uint32_t ks2 = k0 ^ k1 ^ 0x1BD11BDAu;
#define RND(r) { x0 += x1; x1 = rotl32c(x1, (r)); x1 ^= x0; }
  x0 += k0; x1 += k1;
  RND(13) RND(15) RND(26) RND(6)
  x0 += k1; x1 += ks2 + 1u;
  RND(17) RND(29) RND(16) RND(24)
  x0 += ks2; x1 += k0 + 2u;
  RND(13) RND(15) RND(26) RND(6)
  x0 += k0; x1 += k1 + 3u;
  RND(17) RND(29) RND(16) RND(24)
  x0 += k1; x1 += ks2 + 4u;
  RND(13) RND(15) RND(26) RND(6)
  x0 += ks2; x1 += k0 + 5u;
#undef RND
  return U2{x0, x1};
}

// km = split(key(42))[0] under partitionable split: full (y0,y1) of tf(key;0,0)
constexpr U2 KM = tf2x32(0u, 42u, 0u, 0u);

__device__ __forceinline__ float u01_from_bits(uint32_t bits) {
  return __uint_as_float((bits >> 9) | 0x3f800000u) - 1.0f;
}

// softmax(edges,-1)[...,1] in f32; single nontrivial exp via double
// (bit-exact vs reference, proven R4).
__device__ __forceinline__ float prob_edge(float e0, float e1) {
  const float d = e1 - e0;
  const float a = -fabsf(d);
  const float t = (float)exp((double)a);
  return (d >= 0.0f) ? (1.0f / (t + 1.0f)) : (t / (1.0f + t));
}

// Bernoulli mask bit for (o, j): true = edge present (mask adds +1.0f)
__device__ __forceinline__ bool edge_bit(int o, int j, float e0, float e1) {
  const uint32_t n = (uint32_t)(o * INFEAT + j);
  const U2 y = tf2x32(KM.a, KM.b, 0u, n);
  return u01_from_bits(y.a ^ y.b) < prob_edge(e0, e1);
}

__global__ __launch_bounds__(256) void edge_min_fused(
    const float* __restrict__ x,      // [32][2048]
    const float* __restrict__ edges,  // [2048][2048][2]
    float* __restrict__ out) {        // [32][2048]
  __shared__ float thrL[ROWS_PB];
  __shared__ int   cntL[ROWS_PB];
  __shared__ float sx [ROWS_PB][CAP];   // unsorted candidates
  __shared__ int   sj [ROWS_PB][CAP];
  __shared__ float ssx[ROWS_PB][CAP];   // rank-sorted candidates
  __shared__ int   ssj[ROWS_PB][CAP];

  const int tid  = threadIdx.x;
  const int lane = tid & 63;
  const int wv   = tid >> 6;                  // 0..3
  const int rg   = blockIdx.x & 7;            // row group: rows rg*4 .. rg*4+3
  const int og   = blockIdx.x >> 3;           // o group:   o = og*64 + lane
  const int b    = rg * ROWS_PB + wv;         // this wave's row
  const int o    = og * OS_PB + lane;         // this lane's output column

  if (lane == 0) cntL[wv] = 0;
  // lane0's write visible to own wave after lgkmcnt; barrier below covers it.

  // ---- prep: row min + candidate collect (one row per wave) ----
  const float4* x4 = (const float4*)x;
  float4 v[8];
#pragma unroll
  for (int k = 0; k < 8; ++k) v[k] = x4[b * (INFEAT / 4) + k * 64 + lane];
  float lm = INFINITY;
#pragma unroll
  for (int k = 0; k < 8; ++k)
    lm = fminf(lm, fminf(fminf(v[k].x, v[k].y), fminf(v[k].z, v[k].w)));
#pragma unroll
  for (int off = 32; off > 0; off >>= 1)
    lm = fminf(lm, __shfl_xor(lm, off, 64));
  const float thr = lm + 1.0f;                // same f32 rounding as reference
  if (lane == 0) thrL[wv] = thr;

#pragma unroll
  for (int k = 0; k < 8; ++k) {
    const int j0 = (k * 64 + lane) * 4;
    const float c[4] = {v[k].x, v[k].y, v[k].z, v[k].w};
#pragma unroll
    for (int q = 0; q < 4; ++q) {
      if (c[q] < thr) {                       // ~11 hits per row -> cheap atomics
        const int idx = atomicAdd(&cntL[wv], 1);
        if (idx < CAP) { sx[wv][idx] = c[q]; sj[wv][idx] = j0 + q; }
      }
    }
  }
  __syncthreads();

  // ---- rank sort (deterministic: tie-break by column index) ----
  const int cnt = min(cntL[wv], CAP);
  if (lane < cnt) {
    const float xi = sx[wv][lane];
    const int   ji = sj[wv][lane];
    int rank = 0;
    for (int k = 0; k < cnt; ++k) {
      const float xk = sx[wv][k];
      const int   jk = sj[wv][k];
      rank += (xk < xi) || (xk == xi && jk < ji);
    }
    ssx[wv][rank] = xi;
    ssj[wv][rank] = ji;
  }
  __syncthreads();

  // ---- walk: ascending candidates, 8-deep edge prefetch, early exit ----
  const int cnt_raw = cntL[wv];
  const float2* e2 = (const float2*)edges;
  float res;

  if (cnt_raw > CAP) {
    // exact dense fallback -- statistically unreachable, kept for rigor
    float m = INFINITY;
    for (int j = 0; j < INFEAT; ++j) {
      const float2 e = e2[o * INFEAT + j];
      const float bit = edge_bit(o, j, e.x, e.y) ? 1.0f : 0.0f;
      m = fminf(m, x[b * INFEAT + j] + bit);
    }
    res = m;
  } else {
    float m0 = INFINITY;
    bool done = false;
    for (int base = 0; base < cnt && !done; base += 8) {  // cnt wave-uniform
      float cx[8]; int cj[8]; float ce0[8], ce1[8];
#pragma unroll
      for (int k = 0; k < 8; ++k) {
        const bool act = (base + k) < cnt;
        cx[k] = act ? ssx[wv][base + k] : 0.0f;
        cj[k] = act ? ssj[wv][base + k] : 0;
        const float2 e = e2[o * INFEAT + cj[k]];   // j=0 safe when inactive
        ce0[k] = e.x; ce1[k] = e.y;
      }
#pragma unroll
      for (int k = 0; k < 8; ++k) {
        const bool act = (base + k) < cnt;
        if (!done && act && !edge_bit(o, cj[k], ce0[k], ce1[k])) {
          m0 = cx[k];                          // first unmasked = row answer
          done = true;
        }
      }
    }
    res = fminf(m0, thrL[wv]);
  }
  out[b * OUTFEAT + o] = res;
}

extern "C" void kernel_launch(void* const* d_in, const int* in_sizes, int n_in,
                              void* d_out, int out_size, void* d_ws, size_t ws_size,
                              hipStream_t stream) {
  const float* x     = (const float*)d_in[0];   // 32*2048
  const float* edges = (const float*)d_in[1];   // 2048*2048*2
  float* out = (float*)d_out;                   // 32*2048
  (void)in_sizes; (void)n_in; (void)out_size; (void)d_ws; (void)ws_size;

  // grid: 8 row-groups x 32 o-groups = 256 blocks, 256 threads each
  hipLaunchKernelGGL(edge_min_fused, dim3((BATCH / ROWS_PB) * (OUTFEAT / OS_PB)),
                     dim3(256), 0, stream, x, edges, out);
}

// Round 9
// 15.680 us; speedup vs baseline: 3.1409x; 1.5366x over previous
//
#include <hip/hip_runtime.h>
#include <math.h>
#include <stdint.h>

// EdgeLayer: out[b,o] = min_j ( x[b,j] + mask[o,j] ),
// mask = bernoulli(km, softmax(edges)[...,1]), JAX partitionable threefry,
// 32-bit draws = bits1 ^ bits2.  (Bit-exact, proven R4-R8: absmax = 0.)
//
// Identity (proven on-data R6-R8):
//   out[b,o] = min( g_b + 1.0f, min{ x[b,j] : x[b,j] < g_b+1, mask[o,j]=0 } )
// with g_b = min_j x[b,j].  ~11 candidates/row.
//
// R9: probe-parallel walk.  Block = 256 thr = ONE row x 64 o-tasks; each task
// = 4 lanes probing candidates 4-at-a-time (ballot first-zero).  Grid =
// 32 rows x 32 o-groups = 1024 blocks -> 16 waves/CU (4x R8's latency hiding).
// Prep (row min + candidate collect + rank sort) done once per block by all
// 4 waves cooperatively.  Probe math identical to R8 (absmax=0 preserved).
// B=32, IN_F=2048, OUT_F=2048, f32.

#define BATCH 32
#define INFEAT 2048
#define OUTFEAT 2048
#define CAP 64        // P(cnt>64) ~ 1e-30; exact dense fallback kept anyway
#define PW 4          // probe width: lanes per (b,o) task
#define TASKS_PB 64   // o-values per block = 256/PW
#define OGROUPS (OUTFEAT / TASKS_PB)   // 32

struct U2 { uint32_t a, b; };

__host__ __device__ constexpr uint32_t rotl32c(uint32_t x, int r) {
  return (x << r) | (x >> (32 - r));
}

// Exact JAX/Random123 threefry2x32: 20 rounds, both output words.
__host__ __device__ constexpr U2 tf2x32(uint32_t k0, uint32_t k1,
                                        uint32_t x0, uint32_t x1) {
  const uint32_t ks2 = k0 ^ k1 ^ 0x1BD11BDAu;
#define RND(r) { x0 += x1; x1 = rotl32c(x1, (r)); x1 ^= x0; }
  x0 += k0; x1 += k1;
  RND(13) RND(15) RND(26) RND(6)
  x0 += k1; x1 += ks2 + 1u;
  RND(17) RND(29) RND(16) RND(24)
  x0 += ks2; x1 += k0 + 2u;
  RND(13) RND(15) RND(26) RND(6)
  x0 += k0; x1 += k1 + 3u;
  RND(17) RND(29) RND(16) RND(24)
  x0 += k1; x1 += ks2 + 4u;
  RND(13) RND(15) RND(26) RND(6)
  x0 += ks2; x1 += k0 + 5u;
#undef RND
  return U2{x0, x1};
}

// km = split(key(42))[0] under partitionable split: full (y0,y1) of tf(key;0,0)
constexpr U2 KM = tf2x32(0u, 42u, 0u, 0u);

__device__ __forceinline__ float u01_from_bits(uint32_t bits) {
  return __uint_as_float((bits >> 9) | 0x3f800000u) - 1.0f;
}

// softmax(edges,-1)[...,1] in f32; single nontrivial exp via double
// (bit-exact vs reference, proven R4).
__device__ __forceinline__ float prob_edge(float e0, float e1) {
  const float d = e1 - e0;
  const float a = -fabsf(d);
  const float t = (float)exp((double)a);
  return (d >= 0.0f) ? (1.0f / (t + 1.0f)) : (t / (1.0f + t));
}

// Bernoulli mask bit for (o, j): true = edge present (mask adds +1.0f)
__device__ __forceinline__ bool edge_bit(int o, int j, float e0, float e1) {
  const uint32_t n = (uint32_t)(o * INFEAT + j);
  const U2 y = tf2x32(KM.a, KM.b, 0u, n);
  return u01_from_bits(y.a ^ y.b) < prob_edge(e0, e1);
}

__global__ __launch_bounds__(256) void edge_min_probe(
    const float* __restrict__ x,      // [32][2048]
    const float* __restrict__ edges,  // [2048][2048][2]
    float* __restrict__ out) {        // [32][2048]
  __shared__ float sred[4];
  __shared__ int   s_cnt;
  __shared__ float sx [CAP];   // unsorted candidates
  __shared__ int   sjc[CAP];
  __shared__ float ssx[CAP];   // rank-sorted candidates
  __shared__ int   ssj[CAP];

  const int tid  = threadIdx.x;
  const int lane = tid & 63;
  const int wv   = tid >> 6;
  const int b    = blockIdx.x >> 5;          // 0..31 (row)
  const int og   = blockIdx.x & (OGROUPS-1); // 0..31 (o-group)

  if (tid == 0) s_cnt = 0;

  // ---- prep: row min (256 thr x 8 elems, coalesced float4) ----
  const float4* x4 = (const float4*)x;
  const float4 v0 = x4[b * (INFEAT/4) + tid*2];
  const float4 v1 = x4[b * (INFEAT/4) + tid*2 + 1];
  float lm = fminf(fminf(fminf(v0.x, v0.y), fminf(v0.z, v0.w)),
                   fminf(fminf(v1.x, v1.y), fminf(v1.z, v1.w)));
#pragma unroll
  for (int off = 32; off > 0; off >>= 1)
    lm = fminf(lm, __shfl_xor(lm, off, 64));
  if (lane == 0) sred[wv] = lm;
  __syncthreads();
  const float thr = fminf(fminf(sred[0], sred[1]),
                          fminf(sred[2], sred[3])) + 1.0f;  // g_b + 1, exact

  // ---- candidate collect (thread tid owns columns tid*8 .. tid*8+7) ----
  const float c[8] = {v0.x, v0.y, v0.z, v0.w, v1.x, v1.y, v1.z, v1.w};
#pragma unroll
  for (int q = 0; q < 8; ++q) {
    if (c[q] < thr) {                        // ~11 hits per row
      const int idx = atomicAdd(&s_cnt, 1);
      if (idx < CAP) { sx[idx] = c[q]; sjc[idx] = tid*8 + q; }
    }
  }
  __syncthreads();
  const int cnt_raw = s_cnt;
  const int cnt = min(cnt_raw, CAP);

  // ---- rank sort (deterministic: tie-break by column index) ----
  if (tid < cnt) {
    const float xi = sx[tid];
    const int   ji = sjc[tid];
    int rank = 0;
    for (int k = 0; k < cnt; ++k) {
      const float xk = sx[k];
      const int   jk = sjc[k];
      rank += (xk < xi) || (xk == xi && jk < ji);
    }
    ssx[rank] = xi;
    ssj[rank] = ji;
  }
  __syncthreads();

  // ---- probe-parallel walk: 4 lanes per o, ballot first-zero ----
  const int task = tid >> 2;                 // 0..63
  const int pc   = tid & 3;                  // probe slot within group
  const int o    = og * TASKS_PB + task;
  const float2* e2 = (const float2*)edges;
  float res;

  if (cnt_raw > CAP) {
    // exact dense fallback -- statistically unreachable, kept for rigor
    float m = INFINITY;
    for (int j = pc; j < INFEAT; j += PW) {
      const float2 e = e2[o * INFEAT + j];
      const float bit = edge_bit(o, j, e.x, e.y) ? 1.0f : 0.0f;
      m = fminf(m, x[b * INFEAT + j] + bit);
    }
    m = fminf(m, __shfl_xor(m, 1, 64));
    m = fminf(m, __shfl_xor(m, 2, 64));
    res = m;
  } else {
    int widx = -1;
    for (int r = 0; r * PW < cnt; ++r) {
      const int idx = r * PW + pc;
      const bool act = idx < cnt;
      const int cj = act ? ssj[idx] : 0;         // j=0 safe when inactive
      const float2 e = e2[o * INFEAT + cj];      // gather, 1 load/lane
      const bool bit = act ? edge_bit(o, cj, e.x, e.y) : true;
      const unsigned long long zb = __ballot(!bit);
      const uint32_t nib = (uint32_t)(zb >> (lane & 60)) & 0xFu;
      if (nib) { widx = r * PW + (__ffs((int)nib) - 1); break; }
    }
    // first unmasked candidate's x, else g+1 (all-candidates-masked)
    res = (widx >= 0) ? fminf(ssx[widx], thr) : thr;
  }
  if (pc == 0) out[b * OUTFEAT + o] = res;
}

extern "C" void kernel_launch(void* const* d_in, const int* in_sizes, int n_in,
                              void* d_out, int out_size, void* d_ws, size_t ws_size,
                              hipStream_t stream) {
  const float* x     = (const float*)d_in[0];   // 32*2048
  const float* edges = (const float*)d_in[1];   // 2048*2048*2
  float* out = (float*)d_out;                   // 32*2048
  (void)in_sizes; (void)n_in; (void)out_size; (void)d_ws; (void)ws_size;

  // grid: 32 rows x 32 o-groups = 1024 blocks, 256 threads each
  hipLaunchKernelGGL(edge_min_probe, dim3(BATCH * OGROUPS), dim3(256),
                     0, stream, x, edges, out);
}